// Round 1
// baseline (462.890 us; speedup 1.0000x reference)
//
#include <hip/hip_runtime.h>

// ArcFace head, two-pass:
//   pass 1: fp32 -> bf16 convert of W and F + per-row inverse L2 norms (streaming)
//   pass 2: bf16 MFMA GEMM (m97 structure: global_load_lds width=16, 128x128 tile,
//           BK=32, 2-barrier K-loop) + margin/scale epilogue. XCD-swizzled grid.
// Falls back to the previous verified fused kernel if workspace is too small.

typedef __attribute__((ext_vector_type(8))) short short8;
typedef __attribute__((ext_vector_type(8))) unsigned short u16x8;
typedef __attribute__((ext_vector_type(4))) float f32x4;

#define TH_CONST  (-0.8775825618903728f)   // cos(pi - 0.5)
#define MM_CONST  (0.23971276930210156f)   // sin(pi - 0.5) * 0.5
#define M_MARGIN  0.5f
#define S_SCALE   64.0f
#define KD 512   // feature dim (fixed by problem)

__device__ __forceinline__ unsigned short f2bf(float x) {
    // round-to-nearest-even fp32 -> bf16 (finite gaussian inputs; no NaN path)
    unsigned int u = __float_as_uint(x);
    u += 0x7fffu + ((u >> 16) & 1u);
    return (unsigned short)(u >> 16);
}

// ---------------------------------------------------------------------------
// Pass 1: one wave per row. 64 lanes x 8 floats = 512 = KD.
// Reads fp32 row (coalesced 2x float4/lane), writes bf16 row (16B/lane),
// butterfly-reduces sum-of-squares, lane 0 writes 1/sqrt(ss+eps).
// ---------------------------------------------------------------------------
__global__ __launch_bounds__(256)
void convert_norm_kernel(const float* __restrict__ W,
                         const float* __restrict__ F,
                         unsigned short* __restrict__ Wb,
                         unsigned short* __restrict__ Fb,
                         float* __restrict__ invW,
                         float* __restrict__ invF,
                         const int C, const int B)
{
    const int lane = threadIdx.x & 63;
    int gw = blockIdx.x * 4 + (threadIdx.x >> 6);
    const int stride = gridDim.x * 4;
    const int total = C + B;

    for (int row = gw; row < total; row += stride) {
        const float* src;
        unsigned short* dst;
        float* inv;
        if (row < C) {
            src = W + (size_t)row * KD;
            dst = Wb + (size_t)row * KD;
            inv = invW + row;
        } else {
            const int r = row - C;
            src = F + (size_t)r * KD;
            dst = Fb + (size_t)r * KD;
            inv = invF + r;
        }
        const float4* p = (const float4*)(src + lane * 8);
        float4 v0 = p[0], v1 = p[1];

        float ss = v0.x*v0.x + v0.y*v0.y + v0.z*v0.z + v0.w*v0.w
                 + v1.x*v1.x + v1.y*v1.y + v1.z*v1.z + v1.w*v1.w;

        u16x8 pk;
        pk[0]=f2bf(v0.x); pk[1]=f2bf(v0.y); pk[2]=f2bf(v0.z); pk[3]=f2bf(v0.w);
        pk[4]=f2bf(v1.x); pk[5]=f2bf(v1.y); pk[6]=f2bf(v1.z); pk[7]=f2bf(v1.w);
        *(u16x8*)(dst + lane * 8) = pk;

        ss += __shfl_xor(ss, 1);
        ss += __shfl_xor(ss, 2);
        ss += __shfl_xor(ss, 4);
        ss += __shfl_xor(ss, 8);
        ss += __shfl_xor(ss, 16);
        ss += __shfl_xor(ss, 32);
        if (lane == 0) *inv = 1.0f / sqrtf(ss + 1e-12f);
    }
}

// ---------------------------------------------------------------------------
// Pass 2: bf16 GEMM, m97 structure. Tile 128x128, BK=32, 4 waves (2x2 of 64x64).
// LDS tiles are LINEAR [128 rows][64B] so global_load_lds (wave-uniform dest +
// lane*16) fills them exactly in staging order. 2 barriers per K-step; the
// compiler's vmcnt(0) before s_barrier is the tile-ready wait.
// ---------------------------------------------------------------------------
__device__ __forceinline__ void gload_lds_16(const void* g, void* l) {
    __builtin_amdgcn_global_load_lds(
        (const __attribute__((address_space(1))) unsigned int*)g,
        (__attribute__((address_space(3))) unsigned int*)l,
        16, 0, 0);
}

__global__ __launch_bounds__(256, 2)
void arcface_gemm_kernel(const unsigned short* __restrict__ Fb,   // [B][512] bf16
                         const unsigned short* __restrict__ Wb,   // [C][512] bf16
                         const float* __restrict__ invF,
                         const float* __restrict__ invW,
                         const int*   __restrict__ labels,
                         float*       __restrict__ Out,           // [B][C]
                         const int C, const int GM)
{
    __shared__ unsigned short As[128 * 32];   // 8 KB, linear [row][32 bf16]
    __shared__ unsigned short Bs[128 * 32];   // 8 KB
    __shared__ float nF[128];
    __shared__ float nW[128];
    __shared__ int   Ls[128];

    // Bijective XCD swizzle (m204): HW round-robins blockIdx across the 8 XCDs;
    // remap so each XCD gets a contiguous logical chunk, m fastest inside the
    // chunk -> the GM=4 blocks sharing a W-tile hit the same L2.
    const int nwg = gridDim.x;
    const int bid = blockIdx.x;
    const int q   = nwg >> 3, rr = nwg & 7;
    const int xcd = bid & 7,  seq = bid >> 3;
    const int wg  = (xcd < rr ? xcd * (q + 1) : rr * (q + 1) + (xcd - rr) * q) + seq;
    const int mt  = wg % GM;
    const int nt  = wg / GM;

    const int m_base = mt * 128;
    const int n_base = nt * 128;

    const int t    = threadIdx.x;
    const int wave = t >> 6;
    const int lane = t & 63;
    const int wm   = (wave >> 1) * 64;
    const int wn   = (wave & 1) * 64;
    const int quad = lane >> 4;
    const int lcol = lane & 15;

    // epilogue metadata (visible after first in-loop barrier)
    if (t < 128) {
        nF[t] = invF[m_base + t];
        const int c = n_base + t;
        nW[t] = (c < C) ? invW[c] : 0.f;
        Ls[t] = labels[m_base + t];
    }

    // staging: thread t covers tile byte range [t*16, t*16+16) (chunk 0, rows
    // 0..63) and [4096 + t*16, ...) (chunk 1, rows 64..127). Tile row = 64 B.
    const int off0 = t * 16;
    const int ar0  = off0 >> 6;       // 0..63
    const int cb0  = off0 & 63;
    const int ar1  = ar0 + 64;

    const char* gA0 = (const char*)Fb + (size_t)(m_base + ar0) * (KD * 2) + cb0;
    const char* gA1 = (const char*)Fb + (size_t)(m_base + ar1) * (KD * 2) + cb0;
    int b0 = n_base + ar0; if (b0 >= C) b0 = C - 1;   // clamp; stores are guarded
    int b1 = n_base + ar1; if (b1 >= C) b1 = C - 1;
    const char* gB0 = (const char*)Wb + (size_t)b0 * (KD * 2) + cb0;
    const char* gB1 = (const char*)Wb + (size_t)b1 * (KD * 2) + cb0;

    char* lA0 = (char*)As + wave * 1024;          // wave-uniform LDS bases
    char* lA1 = (char*)As + 4096 + wave * 1024;
    char* lB0 = (char*)Bs + wave * 1024;
    char* lB1 = (char*)Bs + 4096 + wave * 1024;

    f32x4 acc[4][4];
    #pragma unroll
    for (int i = 0; i < 4; ++i)
        #pragma unroll
        for (int j = 0; j < 4; ++j)
            acc[i][j] = (f32x4){0.f, 0.f, 0.f, 0.f};

    #pragma unroll 1
    for (int kt = 0; kt < KD / 32; ++kt) {
        gload_lds_16(gA0 + kt * 64, lA0);
        gload_lds_16(gA1 + kt * 64, lA1);
        gload_lds_16(gB0 + kt * 64, lB0);
        gload_lds_16(gB1 + kt * 64, lB1);
        __syncthreads();   // compiler emits vmcnt(0) drain -> tiles ready

        short8 af[4], bfr[4];
        #pragma unroll
        for (int i = 0; i < 4; ++i) {
            af[i]  = *(const short8*)&As[(wm + i * 16 + lcol) * 32 + quad * 8];
            bfr[i] = *(const short8*)&Bs[(wn + i * 16 + lcol) * 32 + quad * 8];
        }
        #pragma unroll
        for (int i = 0; i < 4; ++i)
            #pragma unroll
            for (int j = 0; j < 4; ++j)
                acc[i][j] = __builtin_amdgcn_mfma_f32_16x16x32_bf16(
                                af[i], bfr[j], acc[i][j], 0, 0, 0);
        __syncthreads();   // all fragment reads done before next overwrite
    }

    // epilogue: C/D layout col=lane&15, row=quad*4+reg
    #pragma unroll
    for (int mi = 0; mi < 4; ++mi) {
        const int rl_base = wm + mi * 16 + quad * 4;
        #pragma unroll
        for (int rg = 0; rg < 4; ++rg) {
            const int rl = rl_base + rg;
            const float invf = nF[rl];
            const int lbl = Ls[rl];
            float* orow = Out + (size_t)(m_base + rl) * C;
            #pragma unroll
            for (int ni = 0; ni < 4; ++ni) {
                const int cl = wn + ni * 16 + lcol;
                const int gcol = n_base + cl;
                if (gcol < C) {
                    float v = acc[mi][ni][rg] * invf * nW[cl];
                    v = fminf(1.0f, fmaxf(-1.0f, v));
                    if (gcol == lbl) {
                        v = (v > TH_CONST) ? cosf(acosf(v) + M_MARGIN)
                                           : (v - MM_CONST);
                    }
                    orow[gcol] = S_SCALE * v;
                }
            }
        }
    }
}

// ---------------------------------------------------------------------------
// Fallback: previous verified fused kernel (used only if ws_size too small).
// ---------------------------------------------------------------------------
#define BM 128
#define BN 128
#define BK 32

__global__ __launch_bounds__(256, 2)
void arcface_fused_kernel(const float* __restrict__ F,
                          const int*   __restrict__ labels,
                          const float* __restrict__ W,
                          float*       __restrict__ Out,
                          const int C)
{
    __shared__ unsigned short As[BM][BK];
    __shared__ unsigned short Bs[BN][BK];
    __shared__ float normF[BM];
    __shared__ float normW[BN];
    __shared__ int   Ls[BM];

    const int t = threadIdx.x;
    const int m_base = blockIdx.x * BM;
    const int n_base = blockIdx.y * BN;

    if (t < BM) Ls[t] = labels[m_base + t];

    const int r = t >> 1;
    const int h = t & 1;

    const int lane = t & 63;
    const int wave = t >> 6;
    const int wm = (wave >> 1) * 64;
    const int wn = (wave & 1) * 64;
    const int quad = lane >> 4;
    const int lcol = lane & 15;

    f32x4 acc[4][4];
    #pragma unroll
    for (int i = 0; i < 4; ++i)
        #pragma unroll
        for (int j = 0; j < 4; ++j)
            acc[i][j] = (f32x4){0.f, 0.f, 0.f, 0.f};

    const int cls = n_base + r;
    const bool cvalid = (cls < C);

    const float* Arow = F + (size_t)(m_base + r) * KD + h * 16;
    const float* Wrow = W + (size_t)(cvalid ? cls : 0) * KD + h * 16;

    float sF = 0.f, sW = 0.f;

    for (int kt = 0; kt < KD / BK; ++kt) {
        const float4* ap = (const float4*)(Arow + kt * BK);
        const float4* wp = (const float4*)(Wrow + kt * BK);
        float4 a0 = ap[0], a1 = ap[1], a2 = ap[2], a3 = ap[3];
        float4 w0, w1, w2, w3;
        if (cvalid) { w0 = wp[0]; w1 = wp[1]; w2 = wp[2]; w3 = wp[3]; }
        else { w0 = make_float4(0.f,0.f,0.f,0.f); w1 = w0; w2 = w0; w3 = w0; }

        sF += a0.x*a0.x + a0.y*a0.y + a0.z*a0.z + a0.w*a0.w
            + a1.x*a1.x + a1.y*a1.y + a1.z*a1.z + a1.w*a1.w
            + a2.x*a2.x + a2.y*a2.y + a2.z*a2.z + a2.w*a2.w
            + a3.x*a3.x + a3.y*a3.y + a3.z*a3.z + a3.w*a3.w;
        sW += w0.x*w0.x + w0.y*w0.y + w0.z*w0.z + w0.w*w0.w
            + w1.x*w1.x + w1.y*w1.y + w1.z*w1.z + w1.w*w1.w
            + w2.x*w2.x + w2.y*w2.y + w2.z*w2.z + w2.w*w2.w
            + w3.x*w3.x + w3.y*w3.y + w3.z*w3.z + w3.w*w3.w;

        u16x8 pa0, pa1, pb0, pb1;
        pa0[0]=f2bf(a0.x); pa0[1]=f2bf(a0.y); pa0[2]=f2bf(a0.z); pa0[3]=f2bf(a0.w);
        pa0[4]=f2bf(a1.x); pa0[5]=f2bf(a1.y); pa0[6]=f2bf(a1.z); pa0[7]=f2bf(a1.w);
        pa1[0]=f2bf(a2.x); pa1[1]=f2bf(a2.y); pa1[2]=f2bf(a2.z); pa1[3]=f2bf(a2.w);
        pa1[4]=f2bf(a3.x); pa1[5]=f2bf(a3.y); pa1[6]=f2bf(a3.z); pa1[7]=f2bf(a3.w);
        pb0[0]=f2bf(w0.x); pb0[1]=f2bf(w0.y); pb0[2]=f2bf(w0.z); pb0[3]=f2bf(w0.w);
        pb0[4]=f2bf(w1.x); pb0[5]=f2bf(w1.y); pb0[6]=f2bf(w1.z); pb0[7]=f2bf(w1.w);
        pb1[0]=f2bf(w2.x); pb1[1]=f2bf(w2.y); pb1[2]=f2bf(w2.z); pb1[3]=f2bf(w2.w);
        pb1[4]=f2bf(w3.x); pb1[5]=f2bf(w3.y); pb1[6]=f2bf(w3.z); pb1[7]=f2bf(w3.w);

        __syncthreads();
        *((u16x8*)&As[r][h*16])     = pa0;
        *((u16x8*)&As[r][h*16 + 8]) = pa1;
        *((u16x8*)&Bs[r][h*16])     = pb0;
        *((u16x8*)&Bs[r][h*16 + 8]) = pb1;
        __syncthreads();

        short8 af[4], bfr[4];
        #pragma unroll
        for (int i = 0; i < 4; ++i) {
            af[i]  = *(const short8*)&As[wm + i*16 + lcol][quad*8];
            bfr[i] = *(const short8*)&Bs[wn + i*16 + lcol][quad*8];
        }
        #pragma unroll
        for (int i = 0; i < 4; ++i)
            #pragma unroll
            for (int j = 0; j < 4; ++j)
                acc[i][j] = __builtin_amdgcn_mfma_f32_16x16x32_bf16(
                                af[i], bfr[j], acc[i][j], 0, 0, 0);
    }

    sF += __shfl_xor(sF, 1);
    sW += __shfl_xor(sW, 1);
    if (h == 0) {
        normF[r] = 1.0f / sqrtf(sF + 1e-12f);
        normW[r] = 1.0f / sqrtf(sW + 1e-12f);
    }
    __syncthreads();

    #pragma unroll
    for (int mi = 0; mi < 4; ++mi) {
        const int rl_base = wm + mi*16 + quad*4;
        #pragma unroll
        for (int rg = 0; rg < 4; ++rg) {
            const int rl = rl_base + rg;
            const float invf = normF[rl];
            const int lbl = Ls[rl];
            float* orow = Out + (size_t)(m_base + rl) * C;
            #pragma unroll
            for (int ni = 0; ni < 4; ++ni) {
                const int cl = wn + ni*16 + lcol;
                const int gcol = n_base + cl;
                if (gcol < C) {
                    float v = acc[mi][ni][rg] * invf * normW[cl];
                    v = fminf(1.0f, fmaxf(-1.0f, v));
                    if (gcol == lbl) {
                        v = (v > TH_CONST) ? cosf(acosf(v) + M_MARGIN)
                                           : (v - MM_CONST);
                    }
                    orow[gcol] = S_SCALE * v;
                }
            }
        }
    }
}

// ---------------------------------------------------------------------------
extern "C" void kernel_launch(void* const* d_in, const int* in_sizes, int n_in,
                              void* d_out, int out_size, void* d_ws, size_t ws_size,
                              hipStream_t stream) {
    const float* F      = (const float*)d_in[0];
    const int*   labels = (const int*)d_in[1];
    const float* W      = (const float*)d_in[2];
    float*       Out    = (float*)d_out;

    const int B = in_sizes[1];          // 512
    const int C = in_sizes[2] / KD;     // 100000

    // workspace layout (256B-aligned chunks)
    const size_t a = 255;
    size_t offWb = 0;
    size_t szWb  = (size_t)C * KD * sizeof(unsigned short);
    size_t offFb = (offWb + szWb + a) & ~a;
    size_t szFb  = (size_t)B * KD * sizeof(unsigned short);
    size_t offIW = (offFb + szFb + a) & ~a;
    size_t szIW  = (size_t)C * sizeof(float);
    size_t offIF = (offIW + szIW + a) & ~a;
    size_t szIF  = (size_t)B * sizeof(float);
    size_t need  = offIF + szIF;

    if (d_ws != nullptr && ws_size >= need && (B % 128) == 0) {
        unsigned short* Wb   = (unsigned short*)((char*)d_ws + offWb);
        unsigned short* Fb   = (unsigned short*)((char*)d_ws + offFb);
        float*          invW = (float*)((char*)d_ws + offIW);
        float*          invF = (float*)((char*)d_ws + offIF);

        convert_norm_kernel<<<2048, 256, 0, stream>>>(W, F, Wb, Fb, invW, invF, C, B);

        const int GM = B / 128;
        const int NT = (C + 127) / 128;
        arcface_gemm_kernel<<<GM * NT, 256, 0, stream>>>(Fb, Wb, invF, invW,
                                                         labels, Out, C, GM);
    } else {
        dim3 grid(B / BM, (C + BN - 1) / BN);
        arcface_fused_kernel<<<grid, dim3(256), 0, stream>>>(F, labels, W, Out, C);
    }
}

// Round 2
// 448.810 us; speedup vs baseline: 1.0314x; 1.0314x over previous
//
#include <hip/hip_runtime.h>

// ArcFace head, two-pass:
//   pass 1: fp32 -> bf16 convert of W and F + per-row inverse L2 norms
//           (2 rows per wave-iteration, 64B/lane)
//   pass 2: bf16 MFMA GEMM, 128x128 tile, BK=64 (8 K-iters, 16 barriers total),
//           XOR-swizzled LDS (src-side pre-swizzle for global_load_lds, swizzled
//           ds_read) -> conflict-free; margin/scale epilogue, XCD-swizzled grid.
// Falls back to the verified fused kernel if workspace is too small.

typedef __attribute__((ext_vector_type(8))) short short8;
typedef __attribute__((ext_vector_type(8))) unsigned short u16x8;
typedef __attribute__((ext_vector_type(4))) float f32x4;

#define TH_CONST  (-0.8775825618903728f)   // cos(pi - 0.5)
#define MM_CONST  (0.23971276930210156f)   // sin(pi - 0.5) * 0.5
#define M_MARGIN  0.5f
#define S_SCALE   64.0f
#define KD 512   // feature dim (fixed by problem)

__device__ __forceinline__ unsigned short f2bf(float x) {
    // round-to-nearest-even fp32 -> bf16 (finite gaussian inputs; no NaN path)
    unsigned int u = __float_as_uint(x);
    u += 0x7fffu + ((u >> 16) & 1u);
    return (unsigned short)(u >> 16);
}

// ---------------------------------------------------------------------------
// Pass 1: 2 rows per wave-iteration. 32 lanes x 16 floats = 512 = KD per row.
// ---------------------------------------------------------------------------
__global__ __launch_bounds__(256)
void convert_norm_kernel(const float* __restrict__ W,
                         const float* __restrict__ F,
                         unsigned short* __restrict__ Wb,
                         unsigned short* __restrict__ Fb,
                         float* __restrict__ invW,
                         float* __restrict__ invF,
                         const int C, const int B)
{
    const int lane = threadIdx.x & 63;
    const int half = lane >> 5;          // which row of the pair
    const int l5   = lane & 31;
    const int total  = C + B;
    const int npairs = (total + 1) >> 1;

    int pair = blockIdx.x * 4 + (threadIdx.x >> 6);
    const int stride = gridDim.x * 4;

    for (; pair < npairs; pair += stride) {
        const int row = pair * 2 + half;
        const bool valid = (row < total);
        float ss = 0.f;
        float* inv = nullptr;
        unsigned short* dst = nullptr;

        if (valid) {
            const float* src;
            if (row < C) {
                src = W + (size_t)row * KD;
                dst = Wb + (size_t)row * KD;
                inv = invW + row;
            } else {
                const int r = row - C;
                src = F + (size_t)r * KD;
                dst = Fb + (size_t)r * KD;
                inv = invF + r;
            }
            const float4* p = (const float4*)(src + l5 * 16);
            float4 v0 = p[0], v1 = p[1], v2 = p[2], v3 = p[3];

            ss = v0.x*v0.x + v0.y*v0.y + v0.z*v0.z + v0.w*v0.w
               + v1.x*v1.x + v1.y*v1.y + v1.z*v1.z + v1.w*v1.w
               + v2.x*v2.x + v2.y*v2.y + v2.z*v2.z + v2.w*v2.w
               + v3.x*v3.x + v3.y*v3.y + v3.z*v3.z + v3.w*v3.w;

            u16x8 pk0, pk1;
            pk0[0]=f2bf(v0.x); pk0[1]=f2bf(v0.y); pk0[2]=f2bf(v0.z); pk0[3]=f2bf(v0.w);
            pk0[4]=f2bf(v1.x); pk0[5]=f2bf(v1.y); pk0[6]=f2bf(v1.z); pk0[7]=f2bf(v1.w);
            pk1[0]=f2bf(v2.x); pk1[1]=f2bf(v2.y); pk1[2]=f2bf(v2.z); pk1[3]=f2bf(v2.w);
            pk1[4]=f2bf(v3.x); pk1[5]=f2bf(v3.y); pk1[6]=f2bf(v3.z); pk1[7]=f2bf(v3.w);
            *(u16x8*)(dst + l5 * 16)     = pk0;
            *(u16x8*)(dst + l5 * 16 + 8) = pk1;
        }

        // reduce within each 32-lane half (xor masks < 32 stay in-half)
        ss += __shfl_xor(ss, 1);
        ss += __shfl_xor(ss, 2);
        ss += __shfl_xor(ss, 4);
        ss += __shfl_xor(ss, 8);
        ss += __shfl_xor(ss, 16);
        if (valid && l5 == 0) *inv = 1.0f / sqrtf(ss + 1e-12f);
    }
}

// ---------------------------------------------------------------------------
// Pass 2: bf16 GEMM. Tile 128x128, BK=64, 4 waves (2x2 of 64x64).
// LDS tile rows are 128 B. Bank-conflict-free via XOR swizzle of the 16B slot
// index with (row&7): applied on the GLOBAL source address (global_load_lds
// writes linearly) and again on the ds_read address (same involution).
// ---------------------------------------------------------------------------
__device__ __forceinline__ void gload_lds_16(const void* g, void* l) {
    __builtin_amdgcn_global_load_lds(
        (const __attribute__((address_space(1))) unsigned int*)g,
        (__attribute__((address_space(3))) unsigned int*)l,
        16, 0, 0);
}

__global__ __launch_bounds__(256, 4)
void arcface_gemm_kernel(const unsigned short* __restrict__ Fb,   // [B][512] bf16
                         const unsigned short* __restrict__ Wb,   // [C][512] bf16
                         const float* __restrict__ invF,
                         const float* __restrict__ invW,
                         const int*   __restrict__ labels,
                         float*       __restrict__ Out,           // [B][C]
                         const int C, const int GM)
{
    __shared__ unsigned short As[128 * 64];   // 16 KB, [row][64 bf16] (swizzled)
    __shared__ unsigned short Bs[128 * 64];   // 16 KB
    __shared__ float nF[128];
    __shared__ float nW[128];
    __shared__ int   Ls[128];

    // Bijective XCD swizzle (m204); m fastest inside each XCD chunk.
    const int nwg = gridDim.x;
    const int bid = blockIdx.x;
    const int q   = nwg >> 3, rr = nwg & 7;
    const int xcd = bid & 7,  seq = bid >> 3;
    const int wg  = (xcd < rr ? xcd * (q + 1) : rr * (q + 1) + (xcd - rr) * q) + seq;
    const int mt  = wg % GM;
    const int nt  = wg / GM;

    const int m_base = mt * 128;
    const int n_base = nt * 128;

    const int t    = threadIdx.x;
    const int wave = t >> 6;
    const int lane = t & 63;
    const int wm   = (wave >> 1) * 64;
    const int wn   = (wave & 1) * 64;
    const int quad = lane >> 4;
    const int lcol = lane & 15;

    if (t < 128) {
        nF[t] = invF[m_base + t];
        const int c = n_base + t;
        nW[t] = (c < C) ? invW[c] : 0.f;
        Ls[t] = labels[m_base + t];
    }

    // ---- staging geometry ----
    // call c (0..3) covers tile rows c*32..c*32+31; thread t owns 16 B at
    // linear LDS offset c*4096 + t*16  ->  row = c*32 + (t>>3), slot = t&7.
    // Source column is the swizzled slot: slot' = slot ^ (row&7).
    const int rbase  = t >> 3;                                  // 0..31
    const int colSwz = (((t & 7) ^ ((t >> 3) & 7)) << 4);       // bytes

    const char* gA = (const char*)Fb + (size_t)(m_base + rbase) * (KD * 2) + colSwz;

    unsigned int offB[4];
    #pragma unroll
    for (int c = 0; c < 4; ++c) {
        int rb = n_base + c * 32 + rbase;
        if (rb >= C) rb = C - 1;           // clamp; stores are guarded
        offB[c] = (unsigned int)rb * (KD * 2) + colSwz;
    }
    const char* gWb = (const char*)Wb;

    char* lA = (char*)As + wave * 1024;    // wave-uniform; + c*4096
    char* lB = (char*)Bs + wave * 1024;

    f32x4 acc[4][4];
    #pragma unroll
    for (int i = 0; i < 4; ++i)
        #pragma unroll
        for (int j = 0; j < 4; ++j)
            acc[i][j] = (f32x4){0.f, 0.f, 0.f, 0.f};

    const int sw = (lcol & 7) << 4;        // read-side swizzle (row&7 == lcol&7)

    #pragma unroll 1
    for (int kt = 0; kt < KD / 64; ++kt) {
        const int ko = kt * 128;           // 64 bf16 = 128 B per K-step
        #pragma unroll
        for (int c = 0; c < 4; ++c)
            gload_lds_16(gA + c * 32768 + ko, lA + c * 4096);
        #pragma unroll
        for (int c = 0; c < 4; ++c)
            gload_lds_16(gWb + offB[c] + ko, lB + c * 4096);
        __syncthreads();   // vmcnt(0) drain -> tiles ready

        short8 af[4], bfr[4];
        // ---- k-half 0 (k = 0..31 of this K-step) ----
        #pragma unroll
        for (int i = 0; i < 4; ++i) {
            const int ra = (wm + i * 16 + lcol) * 128;
            const int rb = (wn + i * 16 + lcol) * 128;
            const int co = (quad * 16) ^ sw;
            af[i]  = *(const short8*)((const char*)As + ra + co);
            bfr[i] = *(const short8*)((const char*)Bs + rb + co);
        }
        #pragma unroll
        for (int i = 0; i < 4; ++i)
            #pragma unroll
            for (int j = 0; j < 4; ++j)
                acc[i][j] = __builtin_amdgcn_mfma_f32_16x16x32_bf16(
                                af[i], bfr[j], acc[i][j], 0, 0, 0);
        // ---- k-half 1 (k = 32..63) ----
        #pragma unroll
        for (int i = 0; i < 4; ++i) {
            const int ra = (wm + i * 16 + lcol) * 128;
            const int rb = (wn + i * 16 + lcol) * 128;
            const int co = (64 | (quad * 16)) ^ sw;
            af[i]  = *(const short8*)((const char*)As + ra + co);
            bfr[i] = *(const short8*)((const char*)Bs + rb + co);
        }
        #pragma unroll
        for (int i = 0; i < 4; ++i)
            #pragma unroll
            for (int j = 0; j < 4; ++j)
                acc[i][j] = __builtin_amdgcn_mfma_f32_16x16x32_bf16(
                                af[i], bfr[j], acc[i][j], 0, 0, 0);
        __syncthreads();   // fragment reads done before next overwrite
    }

    // epilogue: C/D layout col=lane&15, row=quad*4+reg
    #pragma unroll
    for (int mi = 0; mi < 4; ++mi) {
        const int rl_base = wm + mi * 16 + quad * 4;
        #pragma unroll
        for (int rg = 0; rg < 4; ++rg) {
            const int rl = rl_base + rg;
            const float invf = nF[rl];
            const int lbl = Ls[rl];
            float* orow = Out + (size_t)(m_base + rl) * C;
            #pragma unroll
            for (int ni = 0; ni < 4; ++ni) {
                const int cl = wn + ni * 16 + lcol;
                const int gcol = n_base + cl;
                if (gcol < C) {
                    float v = acc[mi][ni][rg] * invf * nW[cl];
                    v = fminf(1.0f, fmaxf(-1.0f, v));
                    if (gcol == lbl) {
                        v = (v > TH_CONST) ? cosf(acosf(v) + M_MARGIN)
                                           : (v - MM_CONST);
                    }
                    __builtin_nontemporal_store(S_SCALE * v, &orow[gcol]);
                }
            }
        }
    }
}

// ---------------------------------------------------------------------------
// Fallback: previous verified fused kernel (used only if ws_size too small).
// ---------------------------------------------------------------------------
#define BM 128
#define BN 128
#define BK 32

__global__ __launch_bounds__(256, 2)
void arcface_fused_kernel(const float* __restrict__ F,
                          const int*   __restrict__ labels,
                          const float* __restrict__ W,
                          float*       __restrict__ Out,
                          const int C)
{
    __shared__ unsigned short Asf[BM][BK];
    __shared__ unsigned short Bsf[BN][BK];
    __shared__ float normF[BM];
    __shared__ float normW[BN];
    __shared__ int   Lsf[BM];

    const int t = threadIdx.x;
    const int m_base = blockIdx.x * BM;
    const int n_base = blockIdx.y * BN;

    if (t < BM) Lsf[t] = labels[m_base + t];

    const int r = t >> 1;
    const int h = t & 1;

    const int lane = t & 63;
    const int wave = t >> 6;
    const int wm = (wave >> 1) * 64;
    const int wn = (wave & 1) * 64;
    const int quad = lane >> 4;
    const int lcol = lane & 15;

    f32x4 acc[4][4];
    #pragma unroll
    for (int i = 0; i < 4; ++i)
        #pragma unroll
        for (int j = 0; j < 4; ++j)
            acc[i][j] = (f32x4){0.f, 0.f, 0.f, 0.f};

    const int cls = n_base + r;
    const bool cvalid = (cls < C);

    const float* Arow = F + (size_t)(m_base + r) * KD + h * 16;
    const float* Wrow = W + (size_t)(cvalid ? cls : 0) * KD + h * 16;

    float sF = 0.f, sW = 0.f;

    for (int kt = 0; kt < KD / BK; ++kt) {
        const float4* ap = (const float4*)(Arow + kt * BK);
        const float4* wp = (const float4*)(Wrow + kt * BK);
        float4 a0 = ap[0], a1 = ap[1], a2 = ap[2], a3 = ap[3];
        float4 w0, w1, w2, w3;
        if (cvalid) { w0 = wp[0]; w1 = wp[1]; w2 = wp[2]; w3 = wp[3]; }
        else { w0 = make_float4(0.f,0.f,0.f,0.f); w1 = w0; w2 = w0; w3 = w0; }

        sF += a0.x*a0.x + a0.y*a0.y + a0.z*a0.z + a0.w*a0.w
            + a1.x*a1.x + a1.y*a1.y + a1.z*a1.z + a1.w*a1.w
            + a2.x*a2.x + a2.y*a2.y + a2.z*a2.z + a2.w*a2.w
            + a3.x*a3.x + a3.y*a3.y + a3.z*a3.z + a3.w*a3.w;
        sW += w0.x*w0.x + w0.y*w0.y + w0.z*w0.z + w0.w*w0.w
            + w1.x*w1.x + w1.y*w1.y + w1.z*w1.z + w1.w*w1.w
            + w2.x*w2.x + w2.y*w2.y + w2.z*w2.z + w2.w*w2.w
            + w3.x*w3.x + w3.y*w3.y + w3.z*w3.z + w3.w*w3.w;

        u16x8 pa0, pa1, pb0, pb1;
        pa0[0]=f2bf(a0.x); pa0[1]=f2bf(a0.y); pa0[2]=f2bf(a0.z); pa0[3]=f2bf(a0.w);
        pa0[4]=f2bf(a1.x); pa0[5]=f2bf(a1.y); pa0[6]=f2bf(a1.z); pa0[7]=f2bf(a1.w);
        pa1[0]=f2bf(a2.x); pa1[1]=f2bf(a2.y); pa1[2]=f2bf(a2.z); pa1[3]=f2bf(a2.w);
        pa1[4]=f2bf(a3.x); pa1[5]=f2bf(a3.y); pa1[6]=f2bf(a3.z); pa1[7]=f2bf(a3.w);
        pb0[0]=f2bf(w0.x); pb0[1]=f2bf(w0.y); pb0[2]=f2bf(w0.z); pb0[3]=f2bf(w0.w);
        pb0[4]=f2bf(w1.x); pb0[5]=f2bf(w1.y); pb0[6]=f2bf(w1.z); pb0[7]=f2bf(w1.w);
        pb1[0]=f2bf(w2.x); pb1[1]=f2bf(w2.y); pb1[2]=f2bf(w2.z); pb1[3]=f2bf(w2.w);
        pb1[4]=f2bf(w3.x); pb1[5]=f2bf(w3.y); pb1[6]=f2bf(w3.z); pb1[7]=f2bf(w3.w);

        __syncthreads();
        *((u16x8*)&Asf[r][h*16])     = pa0;
        *((u16x8*)&Asf[r][h*16 + 8]) = pa1;
        *((u16x8*)&Bsf[r][h*16])     = pb0;
        *((u16x8*)&Bsf[r][h*16 + 8]) = pb1;
        __syncthreads();

        short8 af[4], bfr[4];
        #pragma unroll
        for (int i = 0; i < 4; ++i) {
            af[i]  = *(const short8*)&Asf[wm + i*16 + lcol][quad*8];
            bfr[i] = *(const short8*)&Bsf[wn + i*16 + lcol][quad*8];
        }
        #pragma unroll
        for (int i = 0; i < 4; ++i)
            #pragma unroll
            for (int j = 0; j < 4; ++j)
                acc[i][j] = __builtin_amdgcn_mfma_f32_16x16x32_bf16(
                                af[i], bfr[j], acc[i][j], 0, 0, 0);
    }

    sF += __shfl_xor(sF, 1);
    sW += __shfl_xor(sW, 1);
    if (h == 0) {
        normF[r] = 1.0f / sqrtf(sF + 1e-12f);
        normW[r] = 1.0f / sqrtf(sW + 1e-12f);
    }
    __syncthreads();

    #pragma unroll
    for (int mi = 0; mi < 4; ++mi) {
        const int rl_base = wm + mi*16 + quad*4;
        #pragma unroll
        for (int rg = 0; rg < 4; ++rg) {
            const int rl = rl_base + rg;
            const float invf = normF[rl];
            const int lbl = Lsf[rl];
            float* orow = Out + (size_t)(m_base + rl) * C;
            #pragma unroll
            for (int ni = 0; ni < 4; ++ni) {
                const int cl = wn + ni*16 + lcol;
                const int gcol = n_base + cl;
                if (gcol < C) {
                    float v = acc[mi][ni][rg] * invf * normW[cl];
                    v = fminf(1.0f, fmaxf(-1.0f, v));
                    if (gcol == lbl) {
                        v = (v > TH_CONST) ? cosf(acosf(v) + M_MARGIN)
                                           : (v - MM_CONST);
                    }
                    orow[gcol] = S_SCALE * v;
                }
            }
        }
    }
}

// ---------------------------------------------------------------------------
extern "C" void kernel_launch(void* const* d_in, const int* in_sizes, int n_in,
                              void* d_out, int out_size, void* d_ws, size_t ws_size,
                              hipStream_t stream) {
    const float* F      = (const float*)d_in[0];
    const int*   labels = (const int*)d_in[1];
    const float* W      = (const float*)d_in[2];
    float*       Out    = (float*)d_out;

    const int B = in_sizes[1];          // 512
    const int C = in_sizes[2] / KD;     // 100000

    // workspace layout (256B-aligned chunks)
    const size_t a = 255;
    size_t offWb = 0;
    size_t szWb  = (size_t)C * KD * sizeof(unsigned short);
    size_t offFb = (offWb + szWb + a) & ~a;
    size_t szFb  = (size_t)B * KD * sizeof(unsigned short);
    size_t offIW = (offFb + szFb + a) & ~a;
    size_t szIW  = (size_t)C * sizeof(float);
    size_t offIF = (offIW + szIW + a) & ~a;
    size_t szIF  = (size_t)B * sizeof(float);
    size_t need  = offIF + szIF;

    if (d_ws != nullptr && ws_size >= need && (B % 128) == 0) {
        unsigned short* Wb   = (unsigned short*)((char*)d_ws + offWb);
        unsigned short* Fb   = (unsigned short*)((char*)d_ws + offFb);
        float*          invW = (float*)((char*)d_ws + offIW);
        float*          invF = (float*)((char*)d_ws + offIF);

        convert_norm_kernel<<<2048, 256, 0, stream>>>(W, F, Wb, Fb, invW, invF, C, B);

        const int GM = B / 128;
        const int NT = (C + 127) / 128;
        arcface_gemm_kernel<<<GM * NT, 256, 0, stream>>>(Fb, Wb, invF, invW,
                                                         labels, Out, C, GM);
    } else {
        dim3 grid(B / BM, (C + BN - 1) / BN);
        arcface_fused_kernel<<<grid, dim3(256), 0, stream>>>(F, labels, W, Out, C);
    }
}